// Round 1
// baseline (955.944 us; speedup 1.0000x reference)
//
#include <hip/hip_runtime.h>
#include <hip/hip_bf16.h>

#define NROW 8192
#define DIM 256

typedef short bf16x8 __attribute__((ext_vector_type(8)));
typedef float f32x4 __attribute__((ext_vector_type(4)));

__device__ __forceinline__ short f2bf(float x) {
    return __builtin_bit_cast(short, __float2bfloat16(x));
}

// ---------------------------------------------------------------------------
// k1: Wh = h @ W (fp32 accum). Epilogue: WhbT[n][j] = bf16(Wh[j][n]) and
//     f[j] += Wh[j][:] . a  (atomic partial per 64-col block).
// grid (128, 4), block 256
// ---------------------------------------------------------------------------
__global__ __launch_bounds__(256) void k1_whgemm(
    const float* __restrict__ h, const float* __restrict__ W,
    const float* __restrict__ a, short* __restrict__ whbT,
    float* __restrict__ f)
{
    __shared__ float hs[64][65];
    __shared__ float wsm[64][65];
    const int tid = threadIdx.x;
    const int tx = tid & 15, ty = tid >> 4;
    const int i0 = blockIdx.x * 64;
    const int n0 = blockIdx.y * 64;

    float acc[4][4];
#pragma unroll
    for (int u = 0; u < 4; ++u)
#pragma unroll
        for (int v = 0; v < 4; ++v) acc[u][v] = 0.f;

    for (int kb = 0; kb < DIM; kb += 64) {
#pragma unroll
        for (int rr = 0; rr < 4; ++rr) {
            int row = rr * 16 + ty;
            *(float4*)&hs[row][tx * 4] =
                *(const float4*)&h[(size_t)(i0 + row) * DIM + kb + tx * 4];
            *(float4*)&wsm[row][tx * 4] =
                *(const float4*)&W[(size_t)(kb + row) * DIM + n0 + tx * 4];
        }
        __syncthreads();
#pragma unroll 8
        for (int kk = 0; kk < 64; ++kk) {
            float av[4], bv[4];
#pragma unroll
            for (int u = 0; u < 4; ++u) av[u] = hs[ty * 4 + u][kk];
#pragma unroll
            for (int v = 0; v < 4; ++v) bv[v] = wsm[kk][tx * 4 + v];
#pragma unroll
            for (int u = 0; u < 4; ++u)
#pragma unroll
                for (int v = 0; v < 4; ++v) acc[u][v] += av[u] * bv[v];
        }
        __syncthreads();
    }

    // park C tile in LDS (reuse hs)
#pragma unroll
    for (int u = 0; u < 4; ++u)
#pragma unroll
        for (int v = 0; v < 4; ++v) hs[ty * 4 + u][tx * 4 + v] = acc[u][v];
    __syncthreads();

    // f partial: 4 threads per row, 16 cols each
    {
        int r = tid >> 2, q = tid & 3;
        float s = 0.f;
#pragma unroll
        for (int c = 0; c < 16; ++c) s += hs[r][q * 16 + c] * a[n0 + q * 16 + c];
        s += __shfl_xor(s, 1);
        s += __shfl_xor(s, 2);
        if (q == 0) atomicAdd(&f[i0 + r], s);
    }

    // WhbT store (transposed, bf16): 4 threads per n-col, 16 j each
    {
        int n = tid >> 2, q = tid & 3;
#pragma unroll
        for (int b = 0; b < 4; ++b) {
            union { short4 s4; short s[4]; } pk;
#pragma unroll
            for (int c = 0; c < 4; ++c)
                pk.s[c] = f2bf(hs[q * 16 + b * 4 + c][n]);
            *(short4*)&whbT[(size_t)(n0 + n) * NROW + i0 + q * 16 + b * 4] = pk.s4;
        }
    }
}

// ---------------------------------------------------------------------------
// k3: per row i: l[i] = sum_j adj>0 ? exp(lrelu(f_i+f_j)) : 0 ;
//     packed[i*128 + jw] bit b <-> adj[i][jw*64+b] > 0
// grid 8192, block 256
// ---------------------------------------------------------------------------
__global__ __launch_bounds__(256) void k3_rowsum(
    const int* __restrict__ adj, const float* __restrict__ f,
    float* __restrict__ l, unsigned long long* __restrict__ packed)
{
    const int i = blockIdx.x;
    const int tid = threadIdx.x;
    const float fi = f[i];
    const int* row = adj + (size_t)i * NROW;
    float sum = 0.f;
#pragma unroll 4
    for (int it = 0; it < 32; ++it) {
        int j = it * 256 + tid;
        int v = row[j];
        float fj = f[j];
        bool p = v > 0;
        float x = fi + fj;
        float e = fmaxf(x, 0.2f * x);
        float t = p ? __expf(e) : 0.f;
        sum += t;
        unsigned long long m = __ballot(p);
        if ((tid & 63) == 0) packed[(size_t)i * 128 + it * 4 + (tid >> 6)] = m;
    }
#pragma unroll
    for (int off = 32; off > 0; off >>= 1) sum += __shfl_xor(sum, off);
    __shared__ float red[4];
    if ((tid & 63) == 0) red[tid >> 6] = sum;
    __syncthreads();
    if (tid == 0) l[i] = red[0] + red[1] + red[2] + red[3];
}

// ---------------------------------------------------------------------------
// k4: main pass. Block = 32 rows (ib) x 128 cols (half g). Sweep all j in
// 64-wide tiles: recompute alpha from f/l/packed, write alpha (jt parity g),
// MFMA-accumulate h_prime = alpha @ Wh via bf16, elu epilogue.
// grid (256, 2), block 256 (4 waves)
// ---------------------------------------------------------------------------
__global__ __launch_bounds__(256) void k4_main(
    const float* __restrict__ f, const float* __restrict__ l,
    const short* __restrict__ whbT,
    const unsigned long long* __restrict__ packed,
    float* __restrict__ out0, float* __restrict__ alpha)
{
    __shared__ short As[32][72];    // alpha tile, bf16, padded
    __shared__ short Bs[128][72];   // WhbT tile, bf16, padded
    __shared__ float fi_s[32];
    __shared__ float inv_s[32];

    const int tid = threadIdx.x;
    const int i0 = blockIdx.x * 32;
    const int g = blockIdx.y;
    const int n0 = g * 128;
    const int lane = tid & 63;
    const int wave = tid >> 6;

    if (tid < 32) {
        fi_s[tid] = f[i0 + tid];
        inv_s[tid] = 1.f / l[i0 + tid];
    }
    __syncthreads();

    // alpha-compute mapping: 8 consecutive j per thread
    const int r = tid >> 3;
    const int j8 = (tid & 7) * 8;
    const float fi = fi_s[r];
    const float invl = inv_s[r];
    const unsigned long long* prow = packed + (size_t)(i0 + r) * 128;
    float* arow = alpha + (size_t)(i0 + r) * NROW;

    // B staging mapping: one n-row per thread pair, 32 j each
    const int bn = tid >> 1;
    const int bh = (tid & 1) * 32;
    const short* bsrc = whbT + (size_t)(n0 + bn) * NROW + bh;

    // MFMA mapping
    const int mtile = wave & 1;          // rows 16*mtile..+16
    const int nb = (wave >> 1) * 64;     // cols within half
    const int am = lane & 15;
    const int quad = lane >> 4;

    f32x4 acc[4] = {};

    for (int jt = 0; jt < 128; ++jt) {
        const int j0 = jt * 64;
        unsigned int bits = (unsigned int)((prow[jt] >> j8) & 0xffULL);
        float4 fa = *(const float4*)&f[j0 + j8];
        float4 fb = *(const float4*)&f[j0 + j8 + 4];
        float fj[8] = {fa.x, fa.y, fa.z, fa.w, fb.x, fb.y, fb.z, fb.w};
        float av[8];
#pragma unroll
        for (int c = 0; c < 8; ++c) {
            float x = fi + fj[c];
            float e = fmaxf(x, 0.2f * x);
            float t = ((bits >> c) & 1u) ? __expf(e) : 0.f;
            av[c] = t * invl;
        }
        if (g == (jt & 1)) {
            float4 s0 = {av[0], av[1], av[2], av[3]};
            float4 s1 = {av[4], av[5], av[6], av[7]};
            *(float4*)&arow[j0 + j8] = s0;
            *(float4*)&arow[j0 + j8 + 4] = s1;
        }
        // prefetch B slice into regs (no LDS touch yet)
        int4 bv[4];
#pragma unroll
        for (int q = 0; q < 4; ++q)
            bv[q] = *(const int4*)(bsrc + j0 + q * 8);

        __syncthreads();   // previous iteration's MFMA reads complete
        {
            bf16x8 apv;
#pragma unroll
            for (int c = 0; c < 8; ++c) apv[c] = f2bf(av[c]);
            *(bf16x8*)&As[r][j8] = apv;
        }
#pragma unroll
        for (int q = 0; q < 4; ++q)
            *(int4*)&Bs[bn][bh + q * 8] = bv[q];
        __syncthreads();   // tiles visible

#pragma unroll
        for (int ks = 0; ks < 2; ++ks) {
            bf16x8 afr = *(const bf16x8*)&As[mtile * 16 + am][ks * 32 + quad * 8];
#pragma unroll
            for (int nt = 0; nt < 4; ++nt) {
                bf16x8 bfr =
                    *(const bf16x8*)&Bs[nb + nt * 16 + am][ks * 32 + quad * 8];
                acc[nt] = __builtin_amdgcn_mfma_f32_16x16x32_bf16(afr, bfr,
                                                                  acc[nt], 0, 0, 0);
            }
        }
    }

    // epilogue: elu(h_prime). C/D layout: col = lane&15, row = quad*4 + reg
#pragma unroll
    for (int nt = 0; nt < 4; ++nt) {
#pragma unroll
        for (int c = 0; c < 4; ++c) {
            int rr = i0 + mtile * 16 + quad * 4 + c;
            int cc = n0 + nb + nt * 16 + am;
            float v = acc[nt][c];
            out0[(size_t)rr * DIM + cc] = v > 0.f ? v : __expf(v) - 1.f;
        }
    }
}

extern "C" void kernel_launch(void* const* d_in, const int* in_sizes, int n_in,
                              void* d_out, int out_size, void* d_ws, size_t ws_size,
                              hipStream_t stream) {
    const float* h = (const float*)d_in[0];
    const int* adj = (const int*)d_in[1];
    const float* W = (const float*)d_in[2];
    const float* a = (const float*)d_in[3];
    float* out0 = (float*)d_out;                        // elu(h_prime) [8192,256]
    float* alpha = out0 + (size_t)NROW * DIM;           // alpha [8192,8192]

    char* ws = (char*)d_ws;
    float* f = (float*)ws;                                       // 32 KB
    float* l = (float*)(ws + 32768);                             // 32 KB
    short* whbT = (short*)(ws + 65536);                          // 4 MB bf16 [256][8192]
    unsigned long long* packed =
        (unsigned long long*)(ws + 65536 + (size_t)NROW * DIM * sizeof(short)); // 8 MB

    hipMemsetAsync(f, 0, NROW * sizeof(float), stream);
    k1_whgemm<<<dim3(NROW / 64, DIM / 64), 256, 0, stream>>>(h, W, a, whbT, f);
    k3_rowsum<<<dim3(NROW), 256, 0, stream>>>(adj, f, l, packed);
    k4_main<<<dim3(NROW / 32, 2), 256, 0, stream>>>(f, l, whbT, packed, out0, alpha);
}

// Round 2
// 813.387 us; speedup vs baseline: 1.1753x; 1.1753x over previous
//
#include <hip/hip_runtime.h>
#include <hip/hip_bf16.h>

#define NROW 8192
#define DIM 256

typedef short bf16x8 __attribute__((ext_vector_type(8)));
typedef float f32x4 __attribute__((ext_vector_type(4)));

__device__ __forceinline__ short f2bf(float x) {
    return __builtin_bit_cast(short, __float2bfloat16(x));
}

// ---------------------------------------------------------------------------
// k1: Wh = h @ W (fp32 accum). Epilogue: WhbT[n][j] = bf16(Wh[j][n]) and
//     f[j] += Wh[j][:] . a  (atomic partial per 64-col block).
// grid (128, 4), block 256
// ---------------------------------------------------------------------------
__global__ __launch_bounds__(256) void k1_whgemm(
    const float* __restrict__ h, const float* __restrict__ W,
    const float* __restrict__ a, short* __restrict__ whbT,
    float* __restrict__ f)
{
    __shared__ float hs[64][65];
    __shared__ float wsm[64][65];
    const int tid = threadIdx.x;
    const int tx = tid & 15, ty = tid >> 4;
    const int i0 = blockIdx.x * 64;
    const int n0 = blockIdx.y * 64;

    float acc[4][4];
#pragma unroll
    for (int u = 0; u < 4; ++u)
#pragma unroll
        for (int v = 0; v < 4; ++v) acc[u][v] = 0.f;

    for (int kb = 0; kb < DIM; kb += 64) {
#pragma unroll
        for (int rr = 0; rr < 4; ++rr) {
            int row = rr * 16 + ty;
            *(float4*)&hs[row][tx * 4] =
                *(const float4*)&h[(size_t)(i0 + row) * DIM + kb + tx * 4];
            *(float4*)&wsm[row][tx * 4] =
                *(const float4*)&W[(size_t)(kb + row) * DIM + n0 + tx * 4];
        }
        __syncthreads();
#pragma unroll 8
        for (int kk = 0; kk < 64; ++kk) {
            float av[4], bv[4];
#pragma unroll
            for (int u = 0; u < 4; ++u) av[u] = hs[ty * 4 + u][kk];
#pragma unroll
            for (int v = 0; v < 4; ++v) bv[v] = wsm[kk][tx * 4 + v];
#pragma unroll
            for (int u = 0; u < 4; ++u)
#pragma unroll
                for (int v = 0; v < 4; ++v) acc[u][v] += av[u] * bv[v];
        }
        __syncthreads();
    }

#pragma unroll
    for (int u = 0; u < 4; ++u)
#pragma unroll
        for (int v = 0; v < 4; ++v) hs[ty * 4 + u][tx * 4 + v] = acc[u][v];
    __syncthreads();

    {
        int r = tid >> 2, q = tid & 3;
        float s = 0.f;
#pragma unroll
        for (int c = 0; c < 16; ++c) s += hs[r][q * 16 + c] * a[n0 + q * 16 + c];
        s += __shfl_xor(s, 1);
        s += __shfl_xor(s, 2);
        if (q == 0) atomicAdd(&f[i0 + r], s);
    }

    {
        int n = tid >> 2, q = tid & 3;
#pragma unroll
        for (int b = 0; b < 4; ++b) {
            union { short4 s4; short s[4]; } pk;
#pragma unroll
            for (int c = 0; c < 4; ++c)
                pk.s[c] = f2bf(hs[q * 16 + b * 4 + c][n]);
            *(short4*)&whbT[(size_t)(n0 + n) * NROW + i0 + q * 16 + b * 4] = pk.s4;
        }
    }
}

// ---------------------------------------------------------------------------
// k3_fused: per row i (one block): read adj (int4), build packed bits
// (consecutive j order, 16-lane shfl-OR tree), compute t=exp(lrelu(fi+fj)),
// keep t in regs, block-reduce l, then stream alpha = t/l (float4 writes).
// No stores inside barrier loops: single reduction barrier per row.
// grid 8192, block 256
// ---------------------------------------------------------------------------
__global__ __launch_bounds__(256) void k3_fused(
    const int* __restrict__ adj, const float* __restrict__ f,
    float* __restrict__ l, unsigned long long* __restrict__ packed,
    float* __restrict__ alpha)
{
    const int i = blockIdx.x;
    const int tid = threadIdx.x;
    const float fi = f[i];
    const int* row = adj + (size_t)i * NROW;

    float4 tv[8];
    float sum = 0.f;
#pragma unroll
    for (int it = 0; it < 8; ++it) {
        const int j = it * 1024 + tid * 4;
        int4 av = *(const int4*)&row[j];
        float4 fv = *(const float4*)&f[j];
        bool p0 = av.x > 0, p1 = av.y > 0, p2 = av.z > 0, p3 = av.w > 0;
        unsigned int nib = (p0 ? 1u : 0u) | (p1 ? 2u : 0u) |
                           (p2 ? 4u : 0u) | (p3 ? 8u : 0u);
        unsigned long long w = (unsigned long long)nib << ((tid & 15) * 4);
        w |= __shfl_xor(w, 1);
        w |= __shfl_xor(w, 2);
        w |= __shfl_xor(w, 4);
        w |= __shfl_xor(w, 8);
        if ((tid & 15) == 0)
            packed[(size_t)i * 128 + it * 16 + (tid >> 4)] = w;

        float x0 = fi + fv.x, x1 = fi + fv.y, x2 = fi + fv.z, x3 = fi + fv.w;
        float4 t;
        t.x = p0 ? __expf(fmaxf(x0, 0.2f * x0)) : 0.f;
        t.y = p1 ? __expf(fmaxf(x1, 0.2f * x1)) : 0.f;
        t.z = p2 ? __expf(fmaxf(x2, 0.2f * x2)) : 0.f;
        t.w = p3 ? __expf(fmaxf(x3, 0.2f * x3)) : 0.f;
        tv[it] = t;
        sum += t.x + t.y + t.z + t.w;
    }

#pragma unroll
    for (int off = 32; off > 0; off >>= 1) sum += __shfl_xor(sum, off);
    __shared__ float red[4];
    if ((tid & 63) == 0) red[tid >> 6] = sum;
    __syncthreads();
    const float total = red[0] + red[1] + red[2] + red[3];
    const float inv = 1.f / total;
    if (tid == 0) l[i] = total;

    float* arow = alpha + (size_t)i * NROW;
#pragma unroll
    for (int it = 0; it < 8; ++it) {
        float4 t = tv[it];
        float4 o = {t.x * inv, t.y * inv, t.z * inv, t.w * inv};
        *(float4*)&arow[it * 1024 + tid * 4] = o;
    }
}

// ---------------------------------------------------------------------------
// k4b: h_prime partial = alpha(recomputed in A-frag layout) @ Wh.
// Barrier-free, LDS-free. Wave = 16 rows x 256 cols (16 n-tiles, 64 acc
// VGPRs). B frags loaded directly from L2-resident whbT. j split 8-ways
// across blockIdx.y; fp32 atomicAdd into zeroed out0.
// grid (128, 8), block 256 (4 waves = 4 row-groups)
// ---------------------------------------------------------------------------
__global__ __launch_bounds__(256) void k4b_gemm(
    const float* __restrict__ f, const float* __restrict__ l,
    const short* __restrict__ whbT,
    const unsigned long long* __restrict__ packed,
    float* __restrict__ out0)
{
    const int tid = threadIdx.x;
    const int wave = tid >> 6;
    const int lane = tid & 63;
    const int lo = lane & 15;       // A row within group / B n within tile / C col
    const int quad = lane >> 4;
    const int quad8 = quad * 8;

    const int i0 = (blockIdx.x * 4 + wave) * 16;    // 16-row group
    const int jbase = blockIdx.y * 1024;            // this block's j strip

    const float fi = f[i0 + lo];
    const float invl = 1.f / l[i0 + lo];
    const unsigned long long* prow = packed + (size_t)(i0 + lo) * 128;
    const size_t nstr = (size_t)lo * NROW;

    f32x4 acc[16] = {};

#pragma unroll 2
    for (int c32 = 0; c32 < 32; ++c32) {
        const int J = jbase + c32 * 32;
        const unsigned long long w = prow[J >> 6];
        const unsigned int bits =
            (unsigned int)(w >> ((J & 32) + quad8)) & 0xffu;

        const float* fp = f + J + quad8;
        float4 fa = *(const float4*)fp;
        float4 fb = *(const float4*)(fp + 4);
        float fj[8] = {fa.x, fa.y, fa.z, fa.w, fb.x, fb.y, fb.z, fb.w};

        bf16x8 afr;
#pragma unroll
        for (int c = 0; c < 8; ++c) {
            float x = fi + fj[c];
            float e = fmaxf(x, 0.2f * x);
            float t = ((bits >> c) & 1u) ? __expf(e) : 0.f;
            afr[c] = f2bf(t * invl);
        }

        const short* bbase = whbT + nstr + J + quad8;
#pragma unroll
        for (int nt = 0; nt < 16; ++nt) {
            bf16x8 bfr = *(const bf16x8*)(bbase + (size_t)nt * 16 * NROW);
            acc[nt] = __builtin_amdgcn_mfma_f32_16x16x32_bf16(afr, bfr,
                                                              acc[nt], 0, 0, 0);
        }
    }

    // C/D layout: col = lane&15, row = quad*4 + reg
#pragma unroll
    for (int nt = 0; nt < 16; ++nt) {
#pragma unroll
        for (int c = 0; c < 4; ++c) {
            int rr = i0 + quad * 4 + c;
            int cc = nt * 16 + lo;
            atomicAdd(&out0[(size_t)rr * DIM + cc], acc[nt][c]);
        }
    }
}

// ---------------------------------------------------------------------------
// k5: in-place elu on out0. grid 2048, block 256 (float4)
// ---------------------------------------------------------------------------
__global__ __launch_bounds__(256) void k5_elu(float* __restrict__ out0)
{
    const int idx = (blockIdx.x * 256 + threadIdx.x) * 4;
    float4 v = *(float4*)&out0[idx];
    v.x = v.x > 0.f ? v.x : __expf(v.x) - 1.f;
    v.y = v.y > 0.f ? v.y : __expf(v.y) - 1.f;
    v.z = v.z > 0.f ? v.z : __expf(v.z) - 1.f;
    v.w = v.w > 0.f ? v.w : __expf(v.w) - 1.f;
    *(float4*)&out0[idx] = v;
}

extern "C" void kernel_launch(void* const* d_in, const int* in_sizes, int n_in,
                              void* d_out, int out_size, void* d_ws, size_t ws_size,
                              hipStream_t stream) {
    const float* h = (const float*)d_in[0];
    const int* adj = (const int*)d_in[1];
    const float* W = (const float*)d_in[2];
    const float* a = (const float*)d_in[3];
    float* out0 = (float*)d_out;                        // elu(h_prime) [8192,256]
    float* alpha = out0 + (size_t)NROW * DIM;           // alpha [8192,8192]

    char* ws = (char*)d_ws;
    float* f = (float*)ws;                                       // 32 KB
    float* l = (float*)(ws + 32768);                             // 32 KB
    short* whbT = (short*)(ws + 65536);                          // 4 MB bf16 [256][8192]
    unsigned long long* packed =
        (unsigned long long*)(ws + 65536 + (size_t)NROW * DIM * sizeof(short)); // 8 MB

    hipMemsetAsync(f, 0, NROW * sizeof(float), stream);
    hipMemsetAsync(out0, 0, (size_t)NROW * DIM * sizeof(float), stream);
    k1_whgemm<<<dim3(NROW / 64, DIM / 64), 256, 0, stream>>>(h, W, a, whbT, f);
    k3_fused<<<dim3(NROW), 256, 0, stream>>>(adj, f, l, packed, alpha);
    k4b_gemm<<<dim3(NROW / 64, 8), 256, 0, stream>>>(f, l, whbT, packed, out0);
    k5_elu<<<dim3(NROW * DIM / 1024), 256, 0, stream>>>(out0);
}

// Round 3
// 794.677 us; speedup vs baseline: 1.2029x; 1.0235x over previous
//
#include <hip/hip_runtime.h>
#include <hip/hip_bf16.h>

#define NROW 8192
#define DIM 256

typedef short bf16x8 __attribute__((ext_vector_type(8)));
typedef float f32x4 __attribute__((ext_vector_type(4)));

__device__ __forceinline__ short f2bf(float x) {
    return __builtin_bit_cast(short, __float2bfloat16(x));
}

// ---------------------------------------------------------------------------
// k1: Wh = h @ W (fp32 accum). Epilogue: WhbT[n][j] = bf16(Wh[j][n]) and
//     f[j] += Wh[j][:] . a  (atomic partial per 64-col block).
// grid (128, 4), block 256
// ---------------------------------------------------------------------------
__global__ __launch_bounds__(256) void k1_whgemm(
    const float* __restrict__ h, const float* __restrict__ W,
    const float* __restrict__ a, short* __restrict__ whbT,
    float* __restrict__ f)
{
    __shared__ float hs[64][65];
    __shared__ float wsm[64][65];
    const int tid = threadIdx.x;
    const int tx = tid & 15, ty = tid >> 4;
    const int i0 = blockIdx.x * 64;
    const int n0 = blockIdx.y * 64;

    float acc[4][4];
#pragma unroll
    for (int u = 0; u < 4; ++u)
#pragma unroll
        for (int v = 0; v < 4; ++v) acc[u][v] = 0.f;

    for (int kb = 0; kb < DIM; kb += 64) {
#pragma unroll
        for (int rr = 0; rr < 4; ++rr) {
            int row = rr * 16 + ty;
            *(float4*)&hs[row][tx * 4] =
                *(const float4*)&h[(size_t)(i0 + row) * DIM + kb + tx * 4];
            *(float4*)&wsm[row][tx * 4] =
                *(const float4*)&W[(size_t)(kb + row) * DIM + n0 + tx * 4];
        }
        __syncthreads();
#pragma unroll 8
        for (int kk = 0; kk < 64; ++kk) {
            float av[4], bv[4];
#pragma unroll
            for (int u = 0; u < 4; ++u) av[u] = hs[ty * 4 + u][kk];
#pragma unroll
            for (int v = 0; v < 4; ++v) bv[v] = wsm[kk][tx * 4 + v];
#pragma unroll
            for (int u = 0; u < 4; ++u)
#pragma unroll
                for (int v = 0; v < 4; ++v) acc[u][v] += av[u] * bv[v];
        }
        __syncthreads();
    }

#pragma unroll
    for (int u = 0; u < 4; ++u)
#pragma unroll
        for (int v = 0; v < 4; ++v) hs[ty * 4 + u][tx * 4 + v] = acc[u][v];
    __syncthreads();

    {
        int r = tid >> 2, q = tid & 3;
        float s = 0.f;
#pragma unroll
        for (int c = 0; c < 16; ++c) s += hs[r][q * 16 + c] * a[n0 + q * 16 + c];
        s += __shfl_xor(s, 1);
        s += __shfl_xor(s, 2);
        if (q == 0) atomicAdd(&f[i0 + r], s);
    }

    {
        int n = tid >> 2, q = tid & 3;
#pragma unroll
        for (int b = 0; b < 4; ++b) {
            union { short4 s4; short s[4]; } pk;
#pragma unroll
            for (int c = 0; c < 4; ++c)
                pk.s[c] = f2bf(hs[q * 16 + b * 4 + c][n]);
            *(short4*)&whbT[(size_t)(n0 + n) * NROW + i0 + q * 16 + b * 4] = pk.s4;
        }
    }
}

// ---------------------------------------------------------------------------
// k3c: one block per row i. Pure stream: read adj (int4), t = exp(lrelu)
// held in regs, one block reduction for l, scale, float4 alpha writes.
// No packing, no shfl trees. grid 8192, block 256
// ---------------------------------------------------------------------------
__global__ __launch_bounds__(256) void k3c_alpha(
    const int* __restrict__ adj, const float* __restrict__ f,
    float* __restrict__ alpha)
{
    const int i = blockIdx.x;
    const int tid = threadIdx.x;
    const float fi = f[i];
    const int* row = adj + (size_t)i * NROW;

    float4 tv[8];
    float sum = 0.f;
#pragma unroll
    for (int it = 0; it < 8; ++it) {
        const int j = it * 1024 + tid * 4;
        int4 av = *(const int4*)&row[j];
        float4 fv = *(const float4*)&f[j];
        float x0 = fi + fv.x, x1 = fi + fv.y, x2 = fi + fv.z, x3 = fi + fv.w;
        float4 t;
        t.x = av.x > 0 ? __expf(fmaxf(x0, 0.2f * x0)) : 0.f;
        t.y = av.y > 0 ? __expf(fmaxf(x1, 0.2f * x1)) : 0.f;
        t.z = av.z > 0 ? __expf(fmaxf(x2, 0.2f * x2)) : 0.f;
        t.w = av.w > 0 ? __expf(fmaxf(x3, 0.2f * x3)) : 0.f;
        tv[it] = t;
        sum += t.x + t.y + t.z + t.w;
    }

#pragma unroll
    for (int off = 32; off > 0; off >>= 1) sum += __shfl_xor(sum, off);
    __shared__ float red[4];
    if ((tid & 63) == 0) red[tid >> 6] = sum;
    __syncthreads();
    const float inv = 1.f / (red[0] + red[1] + red[2] + red[3]);

    float* arow = alpha + (size_t)i * NROW;
#pragma unroll
    for (int it = 0; it < 8; ++it) {
        float4 t = tv[it];
        float4 o = {t.x * inv, t.y * inv, t.z * inv, t.w * inv};
        *(float4*)&arow[it * 1024 + tid * 4] = o;
    }
}

// ---------------------------------------------------------------------------
// k4c: out0 partial = alpha @ Wh. LDS-staged B (shared by 4 waves), A read
// straight from alpha (fp32->bf16) in MFMA A-layout, reg prefetch of next
// tile. Block = 64 rows x 256 cols; j-split 8. fp32 atomicAdd into zeroed
// out0. grid (128, 8), block 256 (wave w = rows i0+w*16..+15, all 16 n-tiles)
// ---------------------------------------------------------------------------
__global__ __launch_bounds__(256) void k4c_gemm(
    const float* __restrict__ alpha, const short* __restrict__ whbT,
    float* __restrict__ out0)
{
    __shared__ short Bs[256 * 40];   // [n][40] shorts (32 used + pad) = 20 KB

    const int tid = threadIdx.x;
    const int wave = tid >> 6;
    const int lane = tid & 63;
    const int lo = lane & 15;        // A row in m-tile / B n in n-tile / C col
    const int quad = lane >> 4;
    const int q8 = quad * 8;

    const int i0 = blockIdx.x * 64;
    const int jbase = blockIdx.y * 1024;

    // A: this lane reads alpha[i0 + wave*16 + lo][jbase + kt*32 + q8 .. +7]
    const float* aptr = alpha + (size_t)(i0 + wave * 16 + lo) * NROW + jbase + q8;
    // B stage: thread t owns whbT row n = tid, 32 shorts (64 B) per tile
    const short* bsrc = whbT + (size_t)tid * NROW + jbase;
    short* bdst = &Bs[tid * 40];

    f32x4 acc[16] = {};

    // prefetch tile 0
    int4 braw[4];
    float4 a0, a1;
#pragma unroll
    for (int c = 0; c < 4; ++c) braw[c] = *(const int4*)(bsrc + c * 8);
    a0 = *(const float4*)aptr;
    a1 = *(const float4*)(aptr + 4);

#pragma unroll 1
    for (int kt = 0; kt < 32; ++kt) {
        __syncthreads();             // previous tile's ds_reads complete
#pragma unroll
        for (int c = 0; c < 4; ++c) *(int4*)&bdst[c * 8] = braw[c];

        const float4 ca0 = a0, ca1 = a1;
        if (kt < 31) {
#pragma unroll
            for (int c = 0; c < 4; ++c)
                braw[c] = *(const int4*)(bsrc + (kt + 1) * 32 + c * 8);
            a0 = *(const float4*)(aptr + (kt + 1) * 32);
            a1 = *(const float4*)(aptr + (kt + 1) * 32 + 4);
        }
        __syncthreads();             // Bs tile visible

        bf16x8 afr;
        afr[0] = f2bf(ca0.x); afr[1] = f2bf(ca0.y);
        afr[2] = f2bf(ca0.z); afr[3] = f2bf(ca0.w);
        afr[4] = f2bf(ca1.x); afr[5] = f2bf(ca1.y);
        afr[6] = f2bf(ca1.z); afr[7] = f2bf(ca1.w);

#pragma unroll
        for (int nt = 0; nt < 16; ++nt) {
            bf16x8 bfr = *(const bf16x8*)&Bs[(nt * 16 + lo) * 40 + q8];
            acc[nt] = __builtin_amdgcn_mfma_f32_16x16x32_bf16(afr, bfr,
                                                              acc[nt], 0, 0, 0);
        }
    }

    // C/D layout: col = lane&15, row = quad*4 + reg
#pragma unroll
    for (int nt = 0; nt < 16; ++nt) {
#pragma unroll
        for (int c = 0; c < 4; ++c) {
            int rr = i0 + wave * 16 + quad * 4 + c;
            int cc = nt * 16 + lo;
            atomicAdd(&out0[(size_t)rr * DIM + cc], acc[nt][c]);
        }
    }
}

// ---------------------------------------------------------------------------
// k5: in-place elu on out0. grid 2048, block 256 (float4)
// ---------------------------------------------------------------------------
__global__ __launch_bounds__(256) void k5_elu(float* __restrict__ out0)
{
    const int idx = (blockIdx.x * 256 + threadIdx.x) * 4;
    float4 v = *(float4*)&out0[idx];
    v.x = v.x > 0.f ? v.x : __expf(v.x) - 1.f;
    v.y = v.y > 0.f ? v.y : __expf(v.y) - 1.f;
    v.z = v.z > 0.f ? v.z : __expf(v.z) - 1.f;
    v.w = v.w > 0.f ? v.w : __expf(v.w) - 1.f;
    *(float4*)&out0[idx] = v;
}

extern "C" void kernel_launch(void* const* d_in, const int* in_sizes, int n_in,
                              void* d_out, int out_size, void* d_ws, size_t ws_size,
                              hipStream_t stream) {
    const float* h = (const float*)d_in[0];
    const int* adj = (const int*)d_in[1];
    const float* W = (const float*)d_in[2];
    const float* a = (const float*)d_in[3];
    float* out0 = (float*)d_out;                        // elu(h_prime) [8192,256]
    float* alpha = out0 + (size_t)NROW * DIM;           // alpha [8192,8192]

    char* ws = (char*)d_ws;
    float* f = (float*)ws;                              // 32 KB
    short* whbT = (short*)(ws + 32768);                 // 4 MB bf16 [256][8192]

    hipMemsetAsync(f, 0, NROW * sizeof(float), stream);
    hipMemsetAsync(out0, 0, (size_t)NROW * DIM * sizeof(float), stream);
    k1_whgemm<<<dim3(NROW / 64, DIM / 64), 256, 0, stream>>>(h, W, a, whbT, f);
    k3c_alpha<<<dim3(NROW), 256, 0, stream>>>(adj, f, alpha);
    k4c_gemm<<<dim3(NROW / 64, 8), 256, 0, stream>>>(alpha, whbT, out0);
    k5_elu<<<dim3(NROW * DIM / 1024), 256, 0, stream>>>(out0);
}